// Round 1
// baseline (2946.307 us; speedup 1.0000x reference)
//
#include <hip/hip_runtime.h>
#include <math.h>

typedef __bf16 bf16;
typedef float f32x4 __attribute__((ext_vector_type(4)));
typedef __bf16 bf16x8 __attribute__((ext_vector_type(8)));
typedef __bf16 bf16x4 __attribute__((ext_vector_type(4)));

#define T_DIM 4096
#define S_DIM 4096
#define D_DIM 512
#define F_DIM 2048
#define NLAYER 4

__device__ __forceinline__ void split2(float v, bf16& h, bf16& l) {
    h = (bf16)v;
    l = (bf16)(v - (float)h);
}

// LDS offset swizzle: element (row, k=q*8+j) lives at row*32 + (q^((row>>1)&3))*8 + j.
// Makes ds_read_b128 fragment reads (16 lanes, 16 consecutive rows, same q) 2-way => free.
__device__ __forceinline__ int swz(int row, int q) {
    return row * 32 + ((q ^ ((row >> 1) & 3)) << 3);
}

// ---------------------------------------------------------------------------
// GEMM: C[M,N] = A[M,K] * B[N,K]^T, inputs pre-split hi/lo bf16.
// acc += Ah*Bh + Ah*Bl + Al*Bh  (split-precision, ~1e-4 rel err)
// EPI: 0 = store f32 (ldc=N), 1 = Cout = Cin + acc (f32, ldc=N),
//      2 = split-store hi/lo bf16 [M,N] (ldd), 3 = split-store transposed [N,M] (ldd=M),
//      4 = relu + split-store [M,N] (ldd)
// ---------------------------------------------------------------------------
template<int BN, int EPI>
__global__ __launch_bounds__(256)
void gemm_nt(const bf16* __restrict__ Ah, const bf16* __restrict__ Al, int lda,
             const bf16* __restrict__ Bh, const bf16* __restrict__ Bl, int ldb,
             int M, int N, int K,
             const float* Cin, float* Cout,
             bf16* __restrict__ Dh, bf16* __restrict__ Dl, int ldd)
{
    constexpr int BM = 128, BK = 32;
    constexpr int NF = BN / 32;
    __shared__ bf16 AsH[BM * BK], AsL[BM * BK], BsH[BN * BK], BsL[BN * BK];

    const int tid  = threadIdx.x;
    const int wave = tid >> 6;
    const int lane = tid & 63;
    const int wm   = (wave >> 1) * 64;
    const int wn   = (wave & 1) * (BN / 2);
    const int bm   = blockIdx.y * BM;
    const int bn   = blockIdx.x * BN;
    const int kq   = lane >> 4;
    const int rr   = lane & 15;

    f32x4 acc[4][NF];
#pragma unroll
    for (int m = 0; m < 4; ++m)
#pragma unroll
        for (int n = 0; n < NF; ++n)
            acc[m][n] = f32x4{0.f, 0.f, 0.f, 0.f};

    for (int k0 = 0; k0 < K; k0 += BK) {
        // stage A tile (128x32) hi+lo
#pragma unroll
        for (int i = 0; i < (BM * BK) / (256 * 8); ++i) {
            int c = i * 256 + tid;
            int row = c >> 2, q = c & 3;
            size_t g = (size_t)(bm + row) * lda + k0 + q * 8;
            int off = swz(row, q);
            *(bf16x8*)&AsH[off] = *(const bf16x8*)&Ah[g];
            *(bf16x8*)&AsL[off] = *(const bf16x8*)&Al[g];
        }
        // stage B tile (BNx32) hi+lo
#pragma unroll
        for (int i = 0; i < (BN * BK) / (256 * 8); ++i) {
            int c = i * 256 + tid;
            int row = c >> 2, q = c & 3;
            size_t g = (size_t)(bn + row) * ldb + k0 + q * 8;
            int off = swz(row, q);
            *(bf16x8*)&BsH[off] = *(const bf16x8*)&Bh[g];
            *(bf16x8*)&BsL[off] = *(const bf16x8*)&Bl[g];
        }
        __syncthreads();

        bf16x8 ah[4], al[4], bh[NF], bl[NF];
#pragma unroll
        for (int m = 0; m < 4; ++m) {
            int off = swz(wm + m * 16 + rr, kq);
            ah[m] = *(const bf16x8*)&AsH[off];
            al[m] = *(const bf16x8*)&AsL[off];
        }
#pragma unroll
        for (int n = 0; n < NF; ++n) {
            int off = swz(wn + n * 16 + rr, kq);
            bh[n] = *(const bf16x8*)&BsH[off];
            bl[n] = *(const bf16x8*)&BsL[off];
        }
#pragma unroll
        for (int m = 0; m < 4; ++m)
#pragma unroll
            for (int n = 0; n < NF; ++n) {
                acc[m][n] = __builtin_amdgcn_mfma_f32_16x16x32_bf16(ah[m], bh[n], acc[m][n], 0, 0, 0);
                acc[m][n] = __builtin_amdgcn_mfma_f32_16x16x32_bf16(ah[m], bl[n], acc[m][n], 0, 0, 0);
                acc[m][n] = __builtin_amdgcn_mfma_f32_16x16x32_bf16(al[m], bh[n], acc[m][n], 0, 0, 0);
            }
        __syncthreads();
    }

    const int r0 = bm + wm + (lane >> 4) * 4;
    const int c0 = bn + wn + rr;
#pragma unroll
    for (int m = 0; m < 4; ++m)
#pragma unroll
        for (int n = 0; n < NF; ++n) {
            const int c = c0 + n * 16;
            if (EPI == 3) {
                bf16x4 hv, lv;
#pragma unroll
                for (int i = 0; i < 4; ++i) {
                    bf16 h, l; split2(acc[m][n][i], h, l);
                    hv[i] = h; lv[i] = l;
                }
                size_t o = (size_t)c * ldd + r0 + m * 16;
                *(bf16x4*)&Dh[o] = hv;
                *(bf16x4*)&Dl[o] = lv;
            } else {
#pragma unroll
                for (int i = 0; i < 4; ++i) {
                    const int r = r0 + m * 16 + i;
                    float v = acc[m][n][i];
                    if (EPI == 0) {
                        Cout[(size_t)r * N + c] = v;
                    } else if (EPI == 1) {
                        Cout[(size_t)r * N + c] = Cin[(size_t)r * N + c] + v;
                    } else {
                        if (EPI == 4) v = v > 0.f ? v : 0.f;
                        bf16 h, l; split2(v, h, l);
                        Dh[(size_t)r * ldd + c] = h;
                        Dl[(size_t)r * ldd + c] = l;
                    }
                }
            }
        }
}

// ---------------------------------------------------------------------------
// Row LayerNorm (mean/std ddof=1) over D=512. One wave per row.
// FINAL=0: write hi/lo bf16 h. FINAL=1: write f32 alpha*h + gamma to out.
// ---------------------------------------------------------------------------
template<int FINAL>
__global__ __launch_bounds__(256)
void norm_rows(const float* __restrict__ x, bf16* __restrict__ hh, bf16* __restrict__ hl,
               float* __restrict__ outF, const float* __restrict__ alphaP,
               const float* __restrict__ gammaP)
{
    const int row  = blockIdx.x * 4 + (threadIdx.x >> 6);
    const int lane = threadIdx.x & 63;
    const float* xr = x + (size_t)row * D_DIM + lane * 8;
    float4 a = *(const float4*)xr;
    float4 b = *(const float4*)(xr + 4);
    float v[8] = {a.x, a.y, a.z, a.w, b.x, b.y, b.z, b.w};
    float s = 0.f;
#pragma unroll
    for (int j = 0; j < 8; ++j) s += v[j];
#pragma unroll
    for (int off = 32; off; off >>= 1) s += __shfl_xor(s, off);
    const float mean = s * (1.f / 512.f);
    float ss = 0.f;
#pragma unroll
    for (int j = 0; j < 8; ++j) { float d = v[j] - mean; ss += d * d; }
#pragma unroll
    for (int off = 32; off; off >>= 1) ss += __shfl_xor(ss, off);
    const float inv = 1.f / (sqrtf(ss * (1.f / 511.f)) + 1e-6f);
    if (FINAL) {
        const float alp = alphaP[0], gam = gammaP[0];
        float o[8];
#pragma unroll
        for (int j = 0; j < 8; ++j) o[j] = alp * ((v[j] - mean) * inv) + gam;
        float4 o0 = {o[0], o[1], o[2], o[3]};
        float4 o1 = {o[4], o[5], o[6], o[7]};
        float* op = outF + (size_t)row * D_DIM + lane * 8;
        *(float4*)op = o0;
        *(float4*)(op + 4) = o1;
    } else {
        bf16x8 hv, lv;
#pragma unroll
        for (int j = 0; j < 8; ++j) {
            float hval = (v[j] - mean) * inv;
            bf16 h, l; split2(hval, h, l);
            hv[j] = h; lv[j] = l;
        }
        size_t o = (size_t)row * D_DIM + lane * 8;
        *(bf16x8*)&hh[o] = hv;
        *(bf16x8*)&hl[o] = lv;
    }
}

// split fp32 -> hi/lo bf16 (encoder_output), 8 elems/thread, exact grid
__global__ __launch_bounds__(256)
void split_f32(const float* __restrict__ in, bf16* __restrict__ oh, bf16* __restrict__ ol)
{
    size_t i = ((size_t)blockIdx.x * 256 + threadIdx.x) * 8;
    float4 a = *(const float4*)&in[i];
    float4 b = *(const float4*)&in[i + 4];
    float v[8] = {a.x, a.y, a.z, a.w, b.x, b.y, b.z, b.w};
    bf16x8 hv, lv;
#pragma unroll
    for (int j = 0; j < 8; ++j) {
        bf16 h, l; split2(v[j], h, l);
        hv[j] = h; lv[j] = l;
    }
    *(bf16x8*)&oh[i] = hv;
    *(bf16x8*)&ol[i] = lv;
}

// transpose [R,C] fp32 -> [C,R] hi/lo bf16, one layer per blockIdx.z
__global__ __launch_bounds__(256)
void transpose_split(const float* __restrict__ in, bf16* __restrict__ oh,
                     bf16* __restrict__ ol, int R, int C)
{
    const size_t zoff = (size_t)blockIdx.z * R * C;
    in += zoff; oh += zoff; ol += zoff;
    __shared__ float tile[32][33];
    const int tx = threadIdx.x & 31, ty = threadIdx.x >> 5;
    const int r0 = blockIdx.y * 32, c0 = blockIdx.x * 32;
#pragma unroll
    for (int i = 0; i < 4; ++i)
        tile[ty + i * 8][tx] = in[(size_t)(r0 + ty + i * 8) * C + c0 + tx];
    __syncthreads();
#pragma unroll
    for (int i = 0; i < 4; ++i) {
        float v = tile[tx][ty + i * 8];
        bf16 h, l; split2(v, h, l);
        size_t o = (size_t)(c0 + ty + i * 8) * R + r0 + tx;
        oh[o] = h; ol[o] = l;
    }
}

// ---------------------------------------------------------------------------
// Row softmax over S=4096 with mask bias, in-place: reads f32 logits row,
// writes P as hi/lo bf16 into the same row (hi at +0, lo at +S bf16 elems;
// fp32 row stride 4S bytes == bf16 row stride 2S elems).
// SELF=1: bias col s uses cm[t][ids[s]]; SELF=0: cm[t][s].
// ---------------------------------------------------------------------------
template<int SELF>
__global__ __launch_bounds__(256)
void softmax_rows(float* __restrict__ logits, const float* __restrict__ cm,
                  const int* __restrict__ ids, float scale)
{
    const int S = S_DIM;
    const int t = blockIdx.x;
    float* row = logits + (size_t)t * S;
    const float* cmrow = cm + (size_t)t * S;
    __shared__ float red[8];
    const int tid = threadIdx.x, wave = tid >> 6, lane = tid & 63;
    float z[16];
    float lmax = -3.0e38f;
#pragma unroll
    for (int j = 0; j < 4; ++j) {
        const int s = j * 1024 + tid * 4;
        float4 v = *(const float4*)&row[s];
        float m0, m1, m2, m3;
        if (SELF) {
            int4 id4 = *(const int4*)&ids[s];
            m0 = cmrow[id4.x]; m1 = cmrow[id4.y];
            m2 = cmrow[id4.z]; m3 = cmrow[id4.w];
        } else {
            float4 mv = *(const float4*)&cmrow[s];
            m0 = mv.x; m1 = mv.y; m2 = mv.z; m3 = mv.w;
        }
        z[j * 4 + 0] = v.x * scale + (m0 - 1.f) * 1e9f;
        z[j * 4 + 1] = v.y * scale + (m1 - 1.f) * 1e9f;
        z[j * 4 + 2] = v.z * scale + (m2 - 1.f) * 1e9f;
        z[j * 4 + 3] = v.w * scale + (m3 - 1.f) * 1e9f;
        lmax = fmaxf(lmax, fmaxf(fmaxf(z[j*4], z[j*4+1]), fmaxf(z[j*4+2], z[j*4+3])));
    }
#pragma unroll
    for (int off = 32; off; off >>= 1) lmax = fmaxf(lmax, __shfl_xor(lmax, off));
    if (lane == 0) red[wave] = lmax;
    __syncthreads();
    const float mx = fmaxf(fmaxf(red[0], red[1]), fmaxf(red[2], red[3]));
    float lsum = 0.f;
#pragma unroll
    for (int q = 0; q < 16; ++q) { z[q] = __expf(z[q] - mx); lsum += z[q]; }
#pragma unroll
    for (int off = 32; off; off >>= 1) lsum += __shfl_xor(lsum, off);
    if (lane == 0) red[4 + wave] = lsum;
    __syncthreads();
    const float inv = 1.f / (red[4] + red[5] + red[6] + red[7]);
    bf16* ph = (bf16*)row;
    bf16* pl = ph + S;
#pragma unroll
    for (int j = 0; j < 4; ++j) {
        const int s = j * 1024 + tid * 4;
        bf16x4 hv, lv;
#pragma unroll
        for (int q = 0; q < 4; ++q) {
            bf16 h, l; split2(z[j * 4 + q] * inv, h, l);
            hv[q] = h; lv[q] = l;
        }
        *(bf16x4*)&ph[s] = hv;
        *(bf16x4*)&pl[s] = lv;
    }
}

// ---------------------------------------------------------------------------
extern "C" void kernel_launch(void* const* d_in, const int* in_sizes, int n_in,
                              void* d_out, int out_size, void* d_ws, size_t ws_size,
                              hipStream_t stream)
{
    (void)in_sizes; (void)n_in; (void)out_size; (void)ws_size;

    const float* x0p  = (const float*)d_in[0];
    const float* encp = (const float*)d_in[1];
    const float* cmp  = (const float*)d_in[2];
    const float* Wsq[8] = {
        (const float*)d_in[3], (const float*)d_in[4], (const float*)d_in[5],
        (const float*)d_in[6], (const float*)d_in[7], (const float*)d_in[8],
        (const float*)d_in[9], (const float*)d_in[10]
    }; // Wq,Wk,Wv,Wo,Cq,Ck,Cv,Co
    const float* W1p = (const float*)d_in[11];
    const float* W2p = (const float*)d_in[12];
    const float* alphap = (const float*)d_in[13];
    const float* gammap = (const float*)d_in[14];
    const int*   idsp   = (const int*)d_in[15];
    float* outp = (float*)d_out;

    // workspace carve-up (~216 MB)
    char* wp = (char*)d_ws;
    auto take = [&](size_t nelem, int esz) -> void* {
        void* p = (void*)wp;
        wp += (nelem * (size_t)esz + 255) & ~(size_t)255;
        return p;
    };
    bf16 *sqTh[8], *sqTl[8];
    for (int t = 0; t < 8; ++t) {
        sqTh[t] = (bf16*)take((size_t)NLAYER * D_DIM * D_DIM, 2);
        sqTl[t] = (bf16*)take((size_t)NLAYER * D_DIM * D_DIM, 2);
    }
    bf16* w1Th = (bf16*)take((size_t)NLAYER * D_DIM * F_DIM, 2);
    bf16* w1Tl = (bf16*)take((size_t)NLAYER * D_DIM * F_DIM, 2);
    bf16* w2Th = (bf16*)take((size_t)NLAYER * D_DIM * F_DIM, 2);
    bf16* w2Tl = (bf16*)take((size_t)NLAYER * D_DIM * F_DIM, 2);
    bf16* hh   = (bf16*)take((size_t)T_DIM * D_DIM, 2);
    bf16* hl   = (bf16*)take((size_t)T_DIM * D_DIM, 2);
    bf16* qh   = (bf16*)take((size_t)T_DIM * D_DIM, 2);
    bf16* ql   = (bf16*)take((size_t)T_DIM * D_DIM, 2);
    bf16* kh   = (bf16*)take((size_t)S_DIM * D_DIM, 2);
    bf16* kl   = (bf16*)take((size_t)S_DIM * D_DIM, 2);
    bf16* vTh  = (bf16*)take((size_t)S_DIM * D_DIM, 2);
    bf16* vTl  = (bf16*)take((size_t)S_DIM * D_DIM, 2);
    bf16* aoh  = (bf16*)take((size_t)T_DIM * D_DIM, 2);
    bf16* aol  = (bf16*)take((size_t)T_DIM * D_DIM, 2);
    bf16* midh = (bf16*)take((size_t)T_DIM * F_DIM, 2);
    bf16* midl = (bf16*)take((size_t)T_DIM * F_DIM, 2);
    bf16* ench = (bf16*)take((size_t)S_DIM * D_DIM, 2);
    bf16* encl = (bf16*)take((size_t)S_DIM * D_DIM, 2);
    float* xbuf   = (float*)take((size_t)T_DIM * D_DIM, 4);
    float* logits = (float*)take((size_t)T_DIM * S_DIM, 4);

    const dim3 B(256);
    const float scale = 0.0441941738241592f; // 1/sqrt(512)

    // weight prep: transpose + hi/lo split (all layers)
    for (int t = 0; t < 8; ++t)
        transpose_split<<<dim3(D_DIM/32, D_DIM/32, NLAYER), B, 0, stream>>>(
            Wsq[t], sqTh[t], sqTl[t], D_DIM, D_DIM);
    transpose_split<<<dim3(F_DIM/32, D_DIM/32, NLAYER), B, 0, stream>>>(
        W1p, w1Th, w1Tl, D_DIM, F_DIM);
    transpose_split<<<dim3(D_DIM/32, F_DIM/32, NLAYER), B, 0, stream>>>(
        W2p, w2Th, w2Tl, F_DIM, D_DIM);
    split_f32<<<dim3((S_DIM * D_DIM / 8) / 256), B, 0, stream>>>(encp, ench, encl);

    const dim3 gN512(D_DIM / 64, T_DIM / 128);    // BN=64 GEMMs, N=512 -> 256 blocks
    const dim3 gLogit(S_DIM / 128, T_DIM / 128);  // 1024 blocks
    const dim3 gFFN1(F_DIM / 128, T_DIM / 128);   // 512 blocks

    for (int l = 0; l < NLAYER; ++l) {
        const size_t wo = (size_t)l * D_DIM * D_DIM;
        const size_t wf = (size_t)l * D_DIM * F_DIM;
        const float* xin = (l == 0) ? x0p : xbuf;

        // ---- self attention ----
        norm_rows<0><<<T_DIM / 4, B, 0, stream>>>(xin, hh, hl, nullptr, nullptr, nullptr);
        gemm_nt<64, 2><<<gN512, B, 0, stream>>>(hh, hl, D_DIM, sqTh[0] + wo, sqTl[0] + wo, D_DIM,
            T_DIM, D_DIM, D_DIM, nullptr, nullptr, qh, ql, D_DIM);
        gemm_nt<64, 2><<<gN512, B, 0, stream>>>(hh, hl, D_DIM, sqTh[1] + wo, sqTl[1] + wo, D_DIM,
            T_DIM, D_DIM, D_DIM, nullptr, nullptr, kh, kl, D_DIM);
        gemm_nt<64, 3><<<gN512, B, 0, stream>>>(hh, hl, D_DIM, sqTh[2] + wo, sqTl[2] + wo, D_DIM,
            T_DIM, D_DIM, D_DIM, nullptr, nullptr, vTh, vTl, T_DIM);
        gemm_nt<128, 0><<<gLogit, B, 0, stream>>>(qh, ql, D_DIM, kh, kl, D_DIM,
            T_DIM, S_DIM, D_DIM, nullptr, logits, nullptr, nullptr, 0);
        softmax_rows<1><<<T_DIM, B, 0, stream>>>(logits, cmp, idsp, scale);
        gemm_nt<64, 2><<<gN512, B, 0, stream>>>((bf16*)logits, (bf16*)logits + S_DIM, 2 * S_DIM,
            vTh, vTl, T_DIM, T_DIM, D_DIM, T_DIM, nullptr, nullptr, aoh, aol, D_DIM);
        gemm_nt<64, 1><<<gN512, B, 0, stream>>>(aoh, aol, D_DIM, sqTh[3] + wo, sqTl[3] + wo, D_DIM,
            T_DIM, D_DIM, D_DIM, xin, xbuf, nullptr, nullptr, 0);

        // ---- cross attention ----
        norm_rows<0><<<T_DIM / 4, B, 0, stream>>>(xbuf, hh, hl, nullptr, nullptr, nullptr);
        gemm_nt<64, 2><<<gN512, B, 0, stream>>>(hh, hl, D_DIM, sqTh[4] + wo, sqTl[4] + wo, D_DIM,
            T_DIM, D_DIM, D_DIM, nullptr, nullptr, qh, ql, D_DIM);
        gemm_nt<64, 2><<<gN512, B, 0, stream>>>(ench, encl, D_DIM, sqTh[5] + wo, sqTl[5] + wo, D_DIM,
            S_DIM, D_DIM, D_DIM, nullptr, nullptr, kh, kl, D_DIM);
        gemm_nt<64, 3><<<gN512, B, 0, stream>>>(ench, encl, D_DIM, sqTh[6] + wo, sqTl[6] + wo, D_DIM,
            S_DIM, D_DIM, D_DIM, nullptr, nullptr, vTh, vTl, S_DIM);
        gemm_nt<128, 0><<<gLogit, B, 0, stream>>>(qh, ql, D_DIM, kh, kl, D_DIM,
            T_DIM, S_DIM, D_DIM, nullptr, logits, nullptr, nullptr, 0);
        softmax_rows<0><<<T_DIM, B, 0, stream>>>(logits, cmp, nullptr, scale);
        gemm_nt<64, 2><<<gN512, B, 0, stream>>>((bf16*)logits, (bf16*)logits + S_DIM, 2 * S_DIM,
            vTh, vTl, S_DIM, T_DIM, D_DIM, S_DIM, nullptr, nullptr, aoh, aol, D_DIM);
        gemm_nt<64, 1><<<gN512, B, 0, stream>>>(aoh, aol, D_DIM, sqTh[7] + wo, sqTl[7] + wo, D_DIM,
            T_DIM, D_DIM, D_DIM, xbuf, xbuf, nullptr, nullptr, 0);

        // ---- FFN ----
        norm_rows<0><<<T_DIM / 4, B, 0, stream>>>(xbuf, hh, hl, nullptr, nullptr, nullptr);
        gemm_nt<128, 4><<<gFFN1, B, 0, stream>>>(hh, hl, D_DIM, w1Th + wf, w1Tl + wf, D_DIM,
            T_DIM, F_DIM, D_DIM, nullptr, nullptr, midh, midl, F_DIM);
        gemm_nt<64, 1><<<gN512, B, 0, stream>>>(midh, midl, F_DIM, w2Th + wf, w2Tl + wf, F_DIM,
            T_DIM, D_DIM, F_DIM, xbuf, xbuf, nullptr, nullptr, 0);
    }

    norm_rows<1><<<T_DIM / 4, B, 0, stream>>>(xbuf, nullptr, nullptr, outp, alphap, gammap);
}

// Round 2
// 1704.966 us; speedup vs baseline: 1.7281x; 1.7281x over previous
//
#include <hip/hip_runtime.h>
#include <math.h>

typedef _Float16 half_t;
typedef unsigned int u32;
typedef float f32x4 __attribute__((ext_vector_type(4)));
typedef _Float16 f16x8 __attribute__((ext_vector_type(8)));
typedef _Float16 f16x4 __attribute__((ext_vector_type(4)));

#define T_DIM 4096
#define S_DIM 4096
#define D_DIM 512
#define F_DIM 2048
#define NLAYER 4

__device__ __forceinline__ void gload16(const void* g, void* l) {
    __builtin_amdgcn_global_load_lds(
        (const __attribute__((address_space(1))) u32*)g,
        (__attribute__((address_space(3))) u32*)l, 16, 0, 0);
}

// ---------------------------------------------------------------------------
// GEMM: C[M,N] = A[M,K] * B[N,K]^T, fp16 inputs, fp32 MFMA accumulate.
// M is always a multiple of 128 (4096 here). grid = gx * (M/128), 1-D,
// XCD-swizzled (grid % 8 == 0 for all our launches).
// EPI: 0 = store f32 (ldc=N), 1 = Cout = Cin + acc (f32, ldc=N),
//      2 = fp16 store [M,N] (ldd), 3 = fp16 transposed store [N,M] (ldd),
//      4 = relu + fp16 store [M,N] (ldd)
// ---------------------------------------------------------------------------
template<int BN, int EPI>
__global__ __launch_bounds__(256)
void gemm_nt(const half_t* __restrict__ A, int lda,
             const half_t* __restrict__ B, int ldb,
             int N, int K, int gx,
             const float* __restrict__ Cin, float* __restrict__ Cout,
             half_t* __restrict__ D, int ldd)
{
    constexpr int BM = 128, BK = 32;
    constexpr int NF = BN / 32;
    __shared__ half_t As[BM * BK], Bs[BN * BK];

    const int tid  = threadIdx.x;
    const int wave = tid >> 6;
    const int lane = tid & 63;

    // XCD-aware swizzle (bijective: gridDim.x % 8 == 0)
    const int nb  = gridDim.x;
    const int bid = blockIdx.x;
    const int nid = (bid & 7) * (nb >> 3) + (bid >> 3);
    const int bx = nid % gx, by = nid / gx;
    const int bm = by * BM, bn = bx * BN;

    const int wm = (wave >> 1) * 64;
    const int wn = (wave & 1) * (BN / 2);
    const int kq = lane >> 4;
    const int rr = lane & 15;
    const int srow = lane >> 2;          // staging: row within 16-row chunk
    const int scol = (lane & 3) << 3;    // staging: col offset in halfs

    f32x4 acc[4][NF];
#pragma unroll
    for (int m = 0; m < 4; ++m)
#pragma unroll
        for (int n = 0; n < NF; ++n)
            acc[m][n] = f32x4{0.f, 0.f, 0.f, 0.f};

    for (int k0 = 0; k0 < K; k0 += BK) {
        // stage A tile (128x32 fp16 = 8KB): 2 chunks of 1KB per wave
#pragma unroll
        for (int c = 0; c < 2; ++c) {
            const half_t* g = A + (size_t)(bm + c * 64 + wave * 16 + srow) * lda + k0 + scol;
            gload16(g, (char*)As + c * 4096 + wave * 1024 + lane * 16);
        }
        // stage B tile (BNx32)
#pragma unroll
        for (int c = 0; c < BN / 64; ++c) {
            const half_t* g = B + (size_t)(bn + c * 64 + wave * 16 + srow) * ldb + k0 + scol;
            gload16(g, (char*)Bs + c * 4096 + wave * 1024 + lane * 16);
        }
        __syncthreads();

        f16x8 af[4], bf[NF];
#pragma unroll
        for (int m = 0; m < 4; ++m)
            af[m] = *(const f16x8*)&As[(wm + m * 16 + rr) * BK + kq * 8];
#pragma unroll
        for (int n = 0; n < NF; ++n)
            bf[n] = *(const f16x8*)&Bs[(wn + n * 16 + rr) * BK + kq * 8];
#pragma unroll
        for (int m = 0; m < 4; ++m)
#pragma unroll
            for (int n = 0; n < NF; ++n)
                acc[m][n] = __builtin_amdgcn_mfma_f32_16x16x32_f16(af[m], bf[n], acc[m][n], 0, 0, 0);
        __syncthreads();
    }

    const int r0 = bm + wm + (lane >> 4) * 4;
    const int c0 = bn + wn + rr;
#pragma unroll
    for (int m = 0; m < 4; ++m)
#pragma unroll
        for (int n = 0; n < NF; ++n) {
            const int c = c0 + n * 16;
            if (EPI == 3) {
                f16x4 hv;
#pragma unroll
                for (int i = 0; i < 4; ++i) hv[i] = (half_t)acc[m][n][i];
                *(f16x4*)&D[(size_t)c * ldd + r0 + m * 16] = hv;
            } else {
#pragma unroll
                for (int i = 0; i < 4; ++i) {
                    const int r = r0 + m * 16 + i;
                    float v = acc[m][n][i];
                    if (EPI == 0) {
                        Cout[(size_t)r * N + c] = v;
                    } else if (EPI == 1) {
                        Cout[(size_t)r * N + c] = Cin[(size_t)r * N + c] + v;
                    } else {
                        if (EPI == 4) v = v > 0.f ? v : 0.f;
                        D[(size_t)r * ldd + c] = (half_t)v;
                    }
                }
            }
        }
}

// ---------------------------------------------------------------------------
// Row LayerNorm (mean/std ddof=1) over D=512. One wave per row.
// FINAL=0: write fp16 h. FINAL=1: write f32 alpha*h + gamma to out.
// ---------------------------------------------------------------------------
template<int FINAL>
__global__ __launch_bounds__(256)
void norm_rows(const float* __restrict__ x, half_t* __restrict__ hh,
               float* __restrict__ outF, const float* __restrict__ alphaP,
               const float* __restrict__ gammaP)
{
    const int row  = blockIdx.x * 4 + (threadIdx.x >> 6);
    const int lane = threadIdx.x & 63;
    const float* xr = x + (size_t)row * D_DIM + lane * 8;
    float4 a = *(const float4*)xr;
    float4 b = *(const float4*)(xr + 4);
    float v[8] = {a.x, a.y, a.z, a.w, b.x, b.y, b.z, b.w};
    float s = 0.f;
#pragma unroll
    for (int j = 0; j < 8; ++j) s += v[j];
#pragma unroll
    for (int off = 32; off; off >>= 1) s += __shfl_xor(s, off);
    const float mean = s * (1.f / 512.f);
    float ss = 0.f;
#pragma unroll
    for (int j = 0; j < 8; ++j) { float d = v[j] - mean; ss += d * d; }
#pragma unroll
    for (int off = 32; off; off >>= 1) ss += __shfl_xor(ss, off);
    const float inv = 1.f / (sqrtf(ss * (1.f / 511.f)) + 1e-6f);
    if (FINAL) {
        const float alp = alphaP[0], gam = gammaP[0];
        float o[8];
#pragma unroll
        for (int j = 0; j < 8; ++j) o[j] = alp * ((v[j] - mean) * inv) + gam;
        float4 o0 = {o[0], o[1], o[2], o[3]};
        float4 o1 = {o[4], o[5], o[6], o[7]};
        float* op = outF + (size_t)row * D_DIM + lane * 8;
        *(float4*)op = o0;
        *(float4*)(op + 4) = o1;
    } else {
        f16x8 hv;
#pragma unroll
        for (int j = 0; j < 8; ++j) hv[j] = (half_t)((v[j] - mean) * inv);
        *(f16x8*)&hh[(size_t)row * D_DIM + lane * 8] = hv;
    }
}

// fp32 -> fp16 cast (encoder_output), 8 elems/thread
__global__ __launch_bounds__(256)
void cast_f16(const float* __restrict__ in, half_t* __restrict__ out)
{
    size_t i = ((size_t)blockIdx.x * 256 + threadIdx.x) * 8;
    float4 a = *(const float4*)&in[i];
    float4 b = *(const float4*)&in[i + 4];
    float v[8] = {a.x, a.y, a.z, a.w, b.x, b.y, b.z, b.w};
    f16x8 o;
#pragma unroll
    for (int j = 0; j < 8; ++j) o[j] = (half_t)v[j];
    *(f16x8*)&out[i] = o;
}

// transpose [R,C] fp32 -> [C,R] fp16 (with scale), one layer per blockIdx.z
__global__ __launch_bounds__(256)
void transpose_cast(const float* __restrict__ in, half_t* __restrict__ out,
                    int R, int C, float scale)
{
    const size_t zoff = (size_t)blockIdx.z * R * C;
    in += zoff; out += zoff;
    __shared__ float tile[32][33];
    const int tx = threadIdx.x & 31, ty = threadIdx.x >> 5;
    const int r0 = blockIdx.y * 32, c0 = blockIdx.x * 32;
#pragma unroll
    for (int i = 0; i < 4; ++i)
        tile[ty + i * 8][tx] = in[(size_t)(r0 + ty + i * 8) * C + c0 + tx];
    __syncthreads();
#pragma unroll
    for (int i = 0; i < 4; ++i)
        out[(size_t)(c0 + ty + i * 8) * R + r0 + tx] = (half_t)(tile[tx][ty + i * 8] * scale);
}

// pack cross & self masks into bits (cm values are 0/1)
__global__ __launch_bounds__(256)
void pack_masks(const float* __restrict__ cm, const int* __restrict__ ids,
                u32* __restrict__ crossb, u32* __restrict__ selfb)
{
    const int t = blockIdx.y;
    const int s = blockIdx.x * 256 + threadIdx.x;
    const float* row = cm + (size_t)t * S_DIM;
    const float cv = row[s];
    const float sv = row[ids[s]];
    unsigned long long bc = __ballot(cv > 0.5f);
    unsigned long long bs = __ballot(sv > 0.5f);
    if ((threadIdx.x & 63) == 0) {
        const size_t w = (size_t)t * (S_DIM / 32) + (s >> 5);
        crossb[w] = (u32)bc; crossb[w + 1] = (u32)(bc >> 32);
        selfb[w]  = (u32)bs; selfb[w + 1]  = (u32)(bs >> 32);
    }
}

// ---------------------------------------------------------------------------
// Row softmax over S=4096 (logits pre-scaled; mask from packed bits),
// in-place: reads f32 logits row, writes P fp16 at row start
// (fp32 row stride == 2S fp16 elems).
// ---------------------------------------------------------------------------
__global__ __launch_bounds__(256)
void softmax_rows(float* __restrict__ logits, const u32* __restrict__ bits)
{
    const int t = blockIdx.x;
    float* row = logits + (size_t)t * S_DIM;
    const u32* bw = bits + (size_t)t * (S_DIM / 32);
    __shared__ float red[8];
    const int tid = threadIdx.x, wave = tid >> 6, lane = tid & 63;
    float z[16];
    float lmax = -3.0e38f;
#pragma unroll
    for (int j = 0; j < 4; ++j) {
        const int s = j * 1024 + tid * 4;
        float4 v = *(const float4*)&row[s];
        const u32 w = bw[s >> 5];
        const int sh = s & 31;
        z[j * 4 + 0] = v.x + (((w >> (sh + 0)) & 1u) ? 0.f : -1e9f);
        z[j * 4 + 1] = v.y + (((w >> (sh + 1)) & 1u) ? 0.f : -1e9f);
        z[j * 4 + 2] = v.z + (((w >> (sh + 2)) & 1u) ? 0.f : -1e9f);
        z[j * 4 + 3] = v.w + (((w >> (sh + 3)) & 1u) ? 0.f : -1e9f);
        lmax = fmaxf(lmax, fmaxf(fmaxf(z[j*4], z[j*4+1]), fmaxf(z[j*4+2], z[j*4+3])));
    }
#pragma unroll
    for (int off = 32; off; off >>= 1) lmax = fmaxf(lmax, __shfl_xor(lmax, off));
    if (lane == 0) red[wave] = lmax;
    __syncthreads();
    const float mx = fmaxf(fmaxf(red[0], red[1]), fmaxf(red[2], red[3]));
    float lsum = 0.f;
#pragma unroll
    for (int q = 0; q < 16; ++q) { z[q] = __expf(z[q] - mx); lsum += z[q]; }
#pragma unroll
    for (int off = 32; off; off >>= 1) lsum += __shfl_xor(lsum, off);
    if (lane == 0) red[4 + wave] = lsum;
    __syncthreads();
    const float inv = 1.f / (red[4] + red[5] + red[6] + red[7]);
    half_t* ph = (half_t*)row;
#pragma unroll
    for (int j = 0; j < 4; ++j) {
        const int s = j * 1024 + tid * 4;
        f16x4 hv;
#pragma unroll
        for (int q = 0; q < 4; ++q) hv[q] = (half_t)(z[j * 4 + q] * inv);
        *(f16x4*)&ph[s] = hv;
    }
}

// ---------------------------------------------------------------------------
extern "C" void kernel_launch(void* const* d_in, const int* in_sizes, int n_in,
                              void* d_out, int out_size, void* d_ws, size_t ws_size,
                              hipStream_t stream)
{
    (void)in_sizes; (void)n_in; (void)out_size; (void)ws_size;

    const float* x0p  = (const float*)d_in[0];
    const float* encp = (const float*)d_in[1];
    const float* cmp  = (const float*)d_in[2];
    const float* Wsq[8] = {
        (const float*)d_in[3], (const float*)d_in[4], (const float*)d_in[5],
        (const float*)d_in[6], (const float*)d_in[7], (const float*)d_in[8],
        (const float*)d_in[9], (const float*)d_in[10]
    }; // Wq,Wk,Wv,Wo,Cq,Ck,Cv,Co
    const float* W1p = (const float*)d_in[11];
    const float* W2p = (const float*)d_in[12];
    const float* alphap = (const float*)d_in[13];
    const float* gammap = (const float*)d_in[14];
    const int*   idsp   = (const int*)d_in[15];
    float* outp = (float*)d_out;

    char* wp = (char*)d_ws;
    auto take = [&](size_t nelem, int esz) -> void* {
        void* p = (void*)wp;
        wp += (nelem * (size_t)esz + 255) & ~(size_t)255;
        return p;
    };
    half_t* wT[8];
    for (int t = 0; t < 8; ++t)
        wT[t] = (half_t*)take((size_t)NLAYER * D_DIM * D_DIM, 2);
    half_t* w1T = (half_t*)take((size_t)NLAYER * D_DIM * F_DIM, 2);
    half_t* w2T = (half_t*)take((size_t)NLAYER * D_DIM * F_DIM, 2);
    half_t* hh   = (half_t*)take((size_t)T_DIM * D_DIM, 2);
    half_t* qb   = (half_t*)take((size_t)T_DIM * D_DIM, 2);
    half_t* kb   = (half_t*)take((size_t)S_DIM * D_DIM, 2);
    half_t* vT   = (half_t*)take((size_t)S_DIM * D_DIM, 2);
    half_t* ao   = (half_t*)take((size_t)T_DIM * D_DIM, 2);
    half_t* mid  = (half_t*)take((size_t)T_DIM * F_DIM, 2);
    half_t* enc16= (half_t*)take((size_t)S_DIM * D_DIM, 2);
    float* xbuf   = (float*)take((size_t)T_DIM * D_DIM, 4);
    float* logits = (float*)take((size_t)T_DIM * S_DIM, 4);
    u32* crossb = (u32*)take((size_t)T_DIM * (S_DIM / 32), 4);
    u32* selfb  = (u32*)take((size_t)T_DIM * (S_DIM / 32), 4);

    const dim3 B(256);
    const float qscale = 0.04419417382415922f; // 1/sqrt(512), folded into Wq/Cq

    // ---- one-time prep ----
    for (int t = 0; t < 8; ++t)
        transpose_cast<<<dim3(D_DIM/32, D_DIM/32, NLAYER), B, 0, stream>>>(
            Wsq[t], wT[t], D_DIM, D_DIM, (t == 0 || t == 4) ? qscale : 1.0f);
    transpose_cast<<<dim3(F_DIM/32, D_DIM/32, NLAYER), B, 0, stream>>>(
        W1p, w1T, D_DIM, F_DIM, 1.0f);
    transpose_cast<<<dim3(D_DIM/32, F_DIM/32, NLAYER), B, 0, stream>>>(
        W2p, w2T, F_DIM, D_DIM, 1.0f);
    cast_f16<<<dim3((S_DIM * D_DIM / 8) / 256), B, 0, stream>>>(encp, enc16);
    pack_masks<<<dim3(S_DIM / 256, T_DIM), B, 0, stream>>>(cmp, idsp, crossb, selfb);

    const int GY = T_DIM / 128;                 // 32
    const dim3 gN512(8 * GY);                   // N=512, BN=64  -> 256 blocks
    const dim3 gLogit(32 * GY);                 // N=4096, BN=128 -> 1024 blocks
    const dim3 gFFN1(16 * GY);                  // N=2048, BN=128 -> 512 blocks

    for (int l = 0; l < NLAYER; ++l) {
        const size_t wo = (size_t)l * D_DIM * D_DIM;
        const size_t wf = (size_t)l * D_DIM * F_DIM;
        const float* xin = (l == 0) ? x0p : xbuf;

        // ---- self attention ----
        norm_rows<0><<<T_DIM / 4, B, 0, stream>>>(xin, hh, nullptr, nullptr, nullptr);
        gemm_nt<64, 2><<<gN512, B, 0, stream>>>(hh, D_DIM, wT[0] + wo, D_DIM,
            D_DIM, D_DIM, 8, nullptr, nullptr, qb, D_DIM);
        gemm_nt<64, 2><<<gN512, B, 0, stream>>>(hh, D_DIM, wT[1] + wo, D_DIM,
            D_DIM, D_DIM, 8, nullptr, nullptr, kb, D_DIM);
        gemm_nt<64, 3><<<gN512, B, 0, stream>>>(hh, D_DIM, wT[2] + wo, D_DIM,
            D_DIM, D_DIM, 8, nullptr, nullptr, vT, T_DIM);
        gemm_nt<128, 0><<<gLogit, B, 0, stream>>>(qb, D_DIM, kb, D_DIM,
            S_DIM, D_DIM, 32, nullptr, logits, nullptr, 0);
        softmax_rows<<<T_DIM, B, 0, stream>>>(logits, selfb);
        gemm_nt<64, 2><<<gN512, B, 0, stream>>>((half_t*)logits, 2 * S_DIM, vT, T_DIM,
            D_DIM, T_DIM, 8, nullptr, nullptr, ao, D_DIM);
        gemm_nt<64, 1><<<gN512, B, 0, stream>>>(ao, D_DIM, wT[3] + wo, D_DIM,
            D_DIM, D_DIM, 8, xin, xbuf, nullptr, 0);

        // ---- cross attention ----
        norm_rows<0><<<T_DIM / 4, B, 0, stream>>>(xbuf, hh, nullptr, nullptr, nullptr);
        gemm_nt<64, 2><<<gN512, B, 0, stream>>>(hh, D_DIM, wT[4] + wo, D_DIM,
            D_DIM, D_DIM, 8, nullptr, nullptr, qb, D_DIM);
        gemm_nt<64, 2><<<gN512, B, 0, stream>>>(enc16, D_DIM, wT[5] + wo, D_DIM,
            D_DIM, D_DIM, 8, nullptr, nullptr, kb, D_DIM);
        gemm_nt<64, 3><<<gN512, B, 0, stream>>>(enc16, D_DIM, wT[6] + wo, D_DIM,
            D_DIM, D_DIM, 8, nullptr, nullptr, vT, S_DIM);
        gemm_nt<128, 0><<<gLogit, B, 0, stream>>>(qb, D_DIM, kb, D_DIM,
            S_DIM, D_DIM, 32, nullptr, logits, nullptr, 0);
        softmax_rows<<<T_DIM, B, 0, stream>>>(logits, crossb);
        gemm_nt<64, 2><<<gN512, B, 0, stream>>>((half_t*)logits, 2 * S_DIM, vT, S_DIM,
            D_DIM, S_DIM, 8, nullptr, nullptr, ao, D_DIM);
        gemm_nt<64, 1><<<gN512, B, 0, stream>>>(ao, D_DIM, wT[7] + wo, D_DIM,
            D_DIM, D_DIM, 8, xbuf, xbuf, nullptr, 0);

        // ---- FFN ----
        norm_rows<0><<<T_DIM / 4, B, 0, stream>>>(xbuf, hh, nullptr, nullptr, nullptr);
        gemm_nt<128, 4><<<gFFN1, B, 0, stream>>>(hh, D_DIM, w1T + wf, D_DIM,
            F_DIM, D_DIM, 16, nullptr, nullptr, mid, F_DIM);
        gemm_nt<64, 1><<<gN512, B, 0, stream>>>(mid, F_DIM, w2T + wf, F_DIM,
            D_DIM, F_DIM, 8, xbuf, xbuf, nullptr, 0);
    }

    norm_rows<1><<<T_DIM / 4, B, 0, stream>>>(xbuf, nullptr, outp, alphap, gammap);
}

// Round 3
// 1403.819 us; speedup vs baseline: 2.0988x; 1.2145x over previous
//
#include <hip/hip_runtime.h>
#include <math.h>

typedef _Float16 half_t;
typedef unsigned int u32;
typedef unsigned short u16;
typedef float f32x4 __attribute__((ext_vector_type(4)));
typedef _Float16 f16x8 __attribute__((ext_vector_type(8)));
typedef _Float16 f16x4 __attribute__((ext_vector_type(4)));

#define T_DIM 4096
#define S_DIM 4096
#define D_DIM 512
#define F_DIM 2048
#define NLAYER 4

__device__ __forceinline__ void gload16(const void* g, void* l) {
    __builtin_amdgcn_global_load_lds(
        (const __attribute__((address_space(1))) u32*)g,
        (__attribute__((address_space(3))) u32*)l, 16, 0, 0);
}

// ---------------------------------------------------------------------------
// GEMM: C[M,N] = A[M,K] * B[N,K]^T, fp16 in, fp32 MFMA acc.
// Double-buffered LDS, one barrier per K-step: stage(t+1) issued before
// compute(t); __syncthreads' vmcnt(0) drain overlaps with the MFMA phase.
// EPI: 0 f32 store | 1 f32 Cin+acc | 2 fp16 [M,N] | 3 fp16 [N,M] (ldd)
//      4 relu fp16 [M,N] | 5 QKV split (D1=q,D2=k row-major 512; D3=vT ldd)
//      6 KV split (D2=k; D3=vT ldd)
// ---------------------------------------------------------------------------
template<int BN, int EPI>
__global__ __launch_bounds__(256)
void gemm_nt(const half_t* __restrict__ A, int lda,
             const half_t* __restrict__ B, int ldb,
             int N, int K, int gx,
             const float* __restrict__ Cin, float* __restrict__ Cout,
             half_t* __restrict__ D1, half_t* __restrict__ D2,
             half_t* __restrict__ D3, int ldd)
{
    constexpr int BM = 128, BK = 32;
    constexpr int NF = BN / 32;
    __shared__ half_t As[2][BM * BK];
    __shared__ half_t Bs[2][BN * BK];

    const int tid  = threadIdx.x;
    const int wave = tid >> 6;
    const int lane = tid & 63;

    // XCD-aware swizzle (bijective: gridDim.x % 8 == 0 for all launches)
    const int nb  = gridDim.x;
    const int bid = blockIdx.x;
    const int nid = (bid & 7) * (nb >> 3) + (bid >> 3);
    const int bx = nid % gx, by = nid / gx;
    const int bm = by * BM, bn = bx * BN;

    const int wm = (wave >> 1) * 64;
    const int wn = (wave & 1) * (BN / 2);
    const int kq = lane >> 4;
    const int rr = lane & 15;
    const int srow = lane >> 2;
    const int scol = (lane & 3) << 3;

    const half_t* Abase = A + (size_t)(bm + wave * 16 + srow) * lda + scol;
    const half_t* Bbase = B + (size_t)(bn + wave * 16 + srow) * ldb + scol;

    f32x4 acc[4][NF];
#pragma unroll
    for (int m = 0; m < 4; ++m)
#pragma unroll
        for (int n = 0; n < NF; ++n)
            acc[m][n] = f32x4{0.f, 0.f, 0.f, 0.f};

    auto stage = [&](int buf, int k0) {
#pragma unroll
        for (int c = 0; c < 2; ++c)
            gload16(Abase + (size_t)c * 64 * lda + k0,
                    (char*)&As[buf][0] + c * 4096 + wave * 1024 + lane * 16);
#pragma unroll
        for (int c = 0; c < BN / 64; ++c)
            gload16(Bbase + (size_t)c * 64 * ldb + k0,
                    (char*)&Bs[buf][0] + c * 4096 + wave * 1024 + lane * 16);
    };

    const int nt = K / BK;
    stage(0, 0);
    int cur = 0;
    for (int t = 0; t < nt; ++t) {
        __syncthreads();                        // buf[cur] ready (drains vmcnt)
        if (t + 1 < nt) stage(cur ^ 1, (t + 1) * BK);  // prefetch next tile
        f16x8 af[4], bf[NF];
#pragma unroll
        for (int m = 0; m < 4; ++m)
            af[m] = *(const f16x8*)&As[cur][(wm + m * 16 + rr) * BK + kq * 8];
#pragma unroll
        for (int n = 0; n < NF; ++n)
            bf[n] = *(const f16x8*)&Bs[cur][(wn + n * 16 + rr) * BK + kq * 8];
#pragma unroll
        for (int m = 0; m < 4; ++m)
#pragma unroll
            for (int n = 0; n < NF; ++n)
                acc[m][n] = __builtin_amdgcn_mfma_f32_16x16x32_f16(af[m], bf[n], acc[m][n], 0, 0, 0);
        cur ^= 1;
    }

    const int r0 = bm + wm + (lane >> 4) * 4;
#pragma unroll
    for (int m = 0; m < 4; ++m)
#pragma unroll
        for (int n = 0; n < NF; ++n) {
            const int c = bn + wn + n * 16 + rr;
            if (EPI == 0 || EPI == 1) {
#pragma unroll
                for (int i = 0; i < 4; ++i) {
                    const int r = r0 + m * 16 + i;
                    const float v = acc[m][n][i];
                    Cout[(size_t)r * N + c] = (EPI == 1) ? (Cin[(size_t)r * N + c] + v) : v;
                }
            } else if (EPI == 2 || EPI == 4) {
#pragma unroll
                for (int i = 0; i < 4; ++i) {
                    float v = acc[m][n][i];
                    if (EPI == 4) v = fmaxf(v, 0.f);
                    D1[(size_t)(r0 + m * 16 + i) * ldd + c] = (half_t)v;
                }
            } else if (EPI == 3) {
                f16x4 hv;
#pragma unroll
                for (int i = 0; i < 4; ++i) hv[i] = (half_t)acc[m][n][i];
                *(f16x4*)&D1[(size_t)c * ldd + r0 + m * 16] = hv;
            } else if (EPI == 5) {
                if (bn < 512) {
#pragma unroll
                    for (int i = 0; i < 4; ++i)
                        D1[(size_t)(r0 + m * 16 + i) * 512 + c] = (half_t)acc[m][n][i];
                } else if (bn < 1024) {
#pragma unroll
                    for (int i = 0; i < 4; ++i)
                        D2[(size_t)(r0 + m * 16 + i) * 512 + (c - 512)] = (half_t)acc[m][n][i];
                } else {
                    f16x4 hv;
#pragma unroll
                    for (int i = 0; i < 4; ++i) hv[i] = (half_t)acc[m][n][i];
                    *(f16x4*)&D3[(size_t)(c - 1024) * ldd + r0 + m * 16] = hv;
                }
            } else { // EPI == 6
                if (bn < 512) {
#pragma unroll
                    for (int i = 0; i < 4; ++i)
                        D2[(size_t)(r0 + m * 16 + i) * 512 + c] = (half_t)acc[m][n][i];
                } else {
                    f16x4 hv;
#pragma unroll
                    for (int i = 0; i < 4; ++i) hv[i] = (half_t)acc[m][n][i];
                    *(f16x4*)&D3[(size_t)(c - 512) * ldd + r0 + m * 16] = hv;
                }
            }
        }
}

// ---------------------------------------------------------------------------
// Row LayerNorm (mean/std ddof=1) over D=512. One wave per row.
// ---------------------------------------------------------------------------
template<int FINAL>
__global__ __launch_bounds__(256)
void norm_rows(const float* __restrict__ x, half_t* __restrict__ hh,
               float* __restrict__ outF, const float* __restrict__ alphaP,
               const float* __restrict__ gammaP)
{
    const int row  = blockIdx.x * 4 + (threadIdx.x >> 6);
    const int lane = threadIdx.x & 63;
    const float* xr = x + (size_t)row * D_DIM + lane * 8;
    float4 a = *(const float4*)xr;
    float4 b = *(const float4*)(xr + 4);
    float v[8] = {a.x, a.y, a.z, a.w, b.x, b.y, b.z, b.w};
    float s = 0.f;
#pragma unroll
    for (int j = 0; j < 8; ++j) s += v[j];
#pragma unroll
    for (int off = 32; off; off >>= 1) s += __shfl_xor(s, off);
    const float mean = s * (1.f / 512.f);
    float ss = 0.f;
#pragma unroll
    for (int j = 0; j < 8; ++j) { float d = v[j] - mean; ss += d * d; }
#pragma unroll
    for (int off = 32; off; off >>= 1) ss += __shfl_xor(ss, off);
    const float inv = 1.f / (sqrtf(ss * (1.f / 511.f)) + 1e-6f);
    if (FINAL) {
        const float alp = alphaP[0], gam = gammaP[0];
        float o[8];
#pragma unroll
        for (int j = 0; j < 8; ++j) o[j] = alp * ((v[j] - mean) * inv) + gam;
        float4 o0 = {o[0], o[1], o[2], o[3]};
        float4 o1 = {o[4], o[5], o[6], o[7]};
        float* op = outF + (size_t)row * D_DIM + lane * 8;
        *(float4*)op = o0;
        *(float4*)(op + 4) = o1;
    } else {
        f16x8 hv;
#pragma unroll
        for (int j = 0; j < 8; ++j) hv[j] = (half_t)((v[j] - mean) * inv);
        *(f16x8*)&hh[(size_t)row * D_DIM + lane * 8] = hv;
    }
}

__global__ __launch_bounds__(256)
void cast_f16(const float* __restrict__ in, half_t* __restrict__ out)
{
    size_t i = ((size_t)blockIdx.x * 256 + threadIdx.x) * 8;
    float4 a = *(const float4*)&in[i];
    float4 b = *(const float4*)&in[i + 4];
    float v[8] = {a.x, a.y, a.z, a.w, b.x, b.y, b.z, b.w};
    f16x8 o;
#pragma unroll
    for (int j = 0; j < 8; ++j) o[j] = (half_t)v[j];
    *(f16x8*)&out[i] = o;
}

// transpose [R,C] fp32 -> [C,R] fp16 (with scale); per-layer strides inZ/outZ
__global__ __launch_bounds__(256)
void transpose_cast(const float* __restrict__ in, half_t* __restrict__ out,
                    int R, int C, float scale, int inZ, int outZ)
{
    in  += (size_t)blockIdx.z * inZ;
    out += (size_t)blockIdx.z * outZ;
    __shared__ float tile[32][33];
    const int tx = threadIdx.x & 31, ty = threadIdx.x >> 5;
    const int r0 = blockIdx.y * 32, c0 = blockIdx.x * 32;
#pragma unroll
    for (int i = 0; i < 4; ++i)
        tile[ty + i * 8][tx] = in[(size_t)(r0 + ty + i * 8) * C + c0 + tx];
    __syncthreads();
#pragma unroll
    for (int i = 0; i < 4; ++i)
        out[(size_t)(c0 + ty + i * 8) * R + r0 + tx] = (half_t)(tile[tx][ty + i * 8] * scale);
}

// ---------------------------------------------------------------------------
// Mask packing: one block per row t. Cross bits from one coalesced pass over
// cm row (built in LDS), self bits gathered from the 512B LDS word array.
// ---------------------------------------------------------------------------
__global__ __launch_bounds__(256)
void pack_masks(const float* __restrict__ cm, const int* __restrict__ ids,
                u32* __restrict__ crossb, u32* __restrict__ selfb)
{
    const int t = blockIdx.x;
    const float* row = cm + (size_t)t * S_DIM;
    __shared__ u32 cb[S_DIM / 32];   // 128 words
    __shared__ u16 sh16[256];
    const int tid = threadIdx.x;
    u32 bits = 0;
#pragma unroll
    for (int q = 0; q < 4; ++q) {
        float4 v = *(const float4*)&row[tid * 16 + q * 4];
        bits |= (v.x > 0.5f ? 1u : 0u) << (q * 4 + 0);
        bits |= (v.y > 0.5f ? 1u : 0u) << (q * 4 + 1);
        bits |= (v.z > 0.5f ? 1u : 0u) << (q * 4 + 2);
        bits |= (v.w > 0.5f ? 1u : 0u) << (q * 4 + 3);
    }
    ((u16*)cb)[tid] = (u16)bits;
    __syncthreads();
    u32 sb = 0;
#pragma unroll
    for (int q = 0; q < 4; ++q) {
        int4 id4 = *(const int4*)&ids[tid * 16 + q * 4];
        sb |= ((cb[id4.x >> 5] >> (id4.x & 31)) & 1u) << (q * 4 + 0);
        sb |= ((cb[id4.y >> 5] >> (id4.y & 31)) & 1u) << (q * 4 + 1);
        sb |= ((cb[id4.z >> 5] >> (id4.z & 31)) & 1u) << (q * 4 + 2);
        sb |= ((cb[id4.w >> 5] >> (id4.w & 31)) & 1u) << (q * 4 + 3);
    }
    sh16[tid] = (u16)sb;
    __syncthreads();
    if (tid < 128) {
        crossb[(size_t)t * 128 + tid] = cb[tid];
        selfb[(size_t)t * 128 + tid]  = (u32)sh16[2 * tid] | ((u32)sh16[2 * tid + 1] << 16);
    }
}

// ---------------------------------------------------------------------------
// Row softmax over S=4096 (logits pre-scaled; mask from packed bits),
// in-place: reads f32 logits row, writes P fp16 at row start.
// ---------------------------------------------------------------------------
__global__ __launch_bounds__(256)
void softmax_rows(float* __restrict__ logits, const u32* __restrict__ bits)
{
    const int t = blockIdx.x;
    float* row = logits + (size_t)t * S_DIM;
    const u32* bw = bits + (size_t)t * (S_DIM / 32);
    __shared__ float red[8];
    const int tid = threadIdx.x, wave = tid >> 6, lane = tid & 63;
    float z[16];
    float lmax = -3.0e38f;
#pragma unroll
    for (int j = 0; j < 4; ++j) {
        const int s = j * 1024 + tid * 4;
        float4 v = *(const float4*)&row[s];
        const u32 w = bw[s >> 5];
        const int sh = s & 31;
        z[j * 4 + 0] = v.x + (((w >> (sh + 0)) & 1u) ? 0.f : -1e9f);
        z[j * 4 + 1] = v.y + (((w >> (sh + 1)) & 1u) ? 0.f : -1e9f);
        z[j * 4 + 2] = v.z + (((w >> (sh + 2)) & 1u) ? 0.f : -1e9f);
        z[j * 4 + 3] = v.w + (((w >> (sh + 3)) & 1u) ? 0.f : -1e9f);
        lmax = fmaxf(lmax, fmaxf(fmaxf(z[j*4], z[j*4+1]), fmaxf(z[j*4+2], z[j*4+3])));
    }
#pragma unroll
    for (int off = 32; off; off >>= 1) lmax = fmaxf(lmax, __shfl_xor(lmax, off));
    if (lane == 0) red[wave] = lmax;
    __syncthreads();
    const float mx = fmaxf(fmaxf(red[0], red[1]), fmaxf(red[2], red[3]));
    float lsum = 0.f;
#pragma unroll
    for (int q = 0; q < 16; ++q) { z[q] = __expf(z[q] - mx); lsum += z[q]; }
#pragma unroll
    for (int off = 32; off; off >>= 1) lsum += __shfl_xor(lsum, off);
    if (lane == 0) red[4 + wave] = lsum;
    __syncthreads();
    const float inv = 1.f / (red[4] + red[5] + red[6] + red[7]);
    half_t* ph = (half_t*)row;
#pragma unroll
    for (int j = 0; j < 4; ++j) {
        const int s = j * 1024 + tid * 4;
        f16x4 hv;
#pragma unroll
        for (int q = 0; q < 4; ++q) hv[q] = (half_t)(z[j * 4 + q] * inv);
        *(f16x4*)&ph[s] = hv;
    }
}

// ---------------------------------------------------------------------------
extern "C" void kernel_launch(void* const* d_in, const int* in_sizes, int n_in,
                              void* d_out, int out_size, void* d_ws, size_t ws_size,
                              hipStream_t stream)
{
    (void)in_sizes; (void)n_in; (void)out_size; (void)ws_size;

    const float* x0p  = (const float*)d_in[0];
    const float* encp = (const float*)d_in[1];
    const float* cmp  = (const float*)d_in[2];
    const float* Wq = (const float*)d_in[3], *Wk = (const float*)d_in[4];
    const float* Wv = (const float*)d_in[5], *Wo = (const float*)d_in[6];
    const float* Cq = (const float*)d_in[7], *Ck = (const float*)d_in[8];
    const float* Cv = (const float*)d_in[9], *Co = (const float*)d_in[10];
    const float* W1p = (const float*)d_in[11];
    const float* W2p = (const float*)d_in[12];
    const float* alphap = (const float*)d_in[13];
    const float* gammap = (const float*)d_in[14];
    const int*   idsp   = (const int*)d_in[15];
    float* outp = (float*)d_out;

    char* wp = (char*)d_ws;
    auto take = [&](size_t nelem, int esz) -> void* {
        void* p = (void*)wp;
        wp += (nelem * (size_t)esz + 255) & ~(size_t)255;
        return p;
    };
    half_t* wqkvT = (half_t*)take((size_t)NLAYER * 1536 * 512, 2);
    half_t* ckvT  = (half_t*)take((size_t)NLAYER * 1024 * 512, 2);
    half_t* cqT   = (half_t*)take((size_t)NLAYER * 512 * 512, 2);
    half_t* woT   = (half_t*)take((size_t)NLAYER * 512 * 512, 2);
    half_t* coT   = (half_t*)take((size_t)NLAYER * 512 * 512, 2);
    half_t* w1T   = (half_t*)take((size_t)NLAYER * D_DIM * F_DIM, 2);
    half_t* w2T   = (half_t*)take((size_t)NLAYER * D_DIM * F_DIM, 2);
    half_t* hh    = (half_t*)take((size_t)T_DIM * D_DIM, 2);
    half_t* qb    = (half_t*)take((size_t)T_DIM * D_DIM, 2);
    half_t* kb    = (half_t*)take((size_t)S_DIM * D_DIM, 2);
    half_t* vT    = (half_t*)take((size_t)S_DIM * D_DIM, 2);
    half_t* ao    = (half_t*)take((size_t)T_DIM * D_DIM, 2);
    half_t* mid   = (half_t*)take((size_t)T_DIM * F_DIM, 2);
    half_t* enc16 = (half_t*)take((size_t)S_DIM * D_DIM, 2);
    float* xbuf   = (float*)take((size_t)T_DIM * D_DIM, 4);
    float* logits = (float*)take((size_t)T_DIM * S_DIM, 4);
    u32* crossb = (u32*)take((size_t)T_DIM * (S_DIM / 32), 4);
    u32* selfb  = (u32*)take((size_t)T_DIM * (S_DIM / 32), 4);

    const dim3 B(256);
    const float qscale = 0.04419417382415922f; // 1/sqrt(512), folded into Wq/Cq

    // ---- one-time prep ----
    const int SQ = 512 * 512, QKVZ = 1536 * 512, KVZ = 1024 * 512, FZ = 512 * 2048;
    transpose_cast<<<dim3(16,16,4), B, 0, stream>>>(Wq, wqkvT,            512, 512, qscale, SQ, QKVZ);
    transpose_cast<<<dim3(16,16,4), B, 0, stream>>>(Wk, wqkvT + SQ,       512, 512, 1.f,    SQ, QKVZ);
    transpose_cast<<<dim3(16,16,4), B, 0, stream>>>(Wv, wqkvT + 2 * SQ,   512, 512, 1.f,    SQ, QKVZ);
    transpose_cast<<<dim3(16,16,4), B, 0, stream>>>(Wo, woT,              512, 512, 1.f,    SQ, SQ);
    transpose_cast<<<dim3(16,16,4), B, 0, stream>>>(Cq, cqT,              512, 512, qscale, SQ, SQ);
    transpose_cast<<<dim3(16,16,4), B, 0, stream>>>(Ck, ckvT,             512, 512, 1.f,    SQ, KVZ);
    transpose_cast<<<dim3(16,16,4), B, 0, stream>>>(Cv, ckvT + SQ,        512, 512, 1.f,    SQ, KVZ);
    transpose_cast<<<dim3(16,16,4), B, 0, stream>>>(Co, coT,              512, 512, 1.f,    SQ, SQ);
    transpose_cast<<<dim3(64,16,4), B, 0, stream>>>(W1p, w1T, 512, 2048, 1.f, FZ, FZ);
    transpose_cast<<<dim3(16,64,4), B, 0, stream>>>(W2p, w2T, 2048, 512, 1.f, FZ, FZ);
    cast_f16<<<dim3((S_DIM * D_DIM / 8) / 256), B, 0, stream>>>(encp, enc16);
    pack_masks<<<dim3(T_DIM), B, 0, stream>>>(cmp, idsp, crossb, selfb);

    for (int l = 0; l < NLAYER; ++l) {
        const float* xin = (l == 0) ? x0p : xbuf;

        // ---- self attention ----
        norm_rows<0><<<T_DIM / 4, B, 0, stream>>>(xin, hh, nullptr, nullptr, nullptr);
        gemm_nt<64, 5><<<dim3(768), B, 0, stream>>>(hh, 512, wqkvT + (size_t)l * QKVZ, 512,
            1536, 512, 24, nullptr, nullptr, qb, kb, vT, 4096);
        gemm_nt<128, 0><<<dim3(1024), B, 0, stream>>>(qb, 512, kb, 512,
            4096, 512, 32, nullptr, logits, nullptr, nullptr, nullptr, 0);
        softmax_rows<<<dim3(T_DIM), B, 0, stream>>>(logits, selfb);
        gemm_nt<64, 2><<<dim3(256), B, 0, stream>>>((half_t*)logits, 8192, vT, 4096,
            512, 4096, 8, nullptr, nullptr, ao, nullptr, nullptr, 512);
        gemm_nt<64, 1><<<dim3(256), B, 0, stream>>>(ao, 512, woT + (size_t)l * SQ, 512,
            512, 512, 8, xin, xbuf, nullptr, nullptr, nullptr, 0);

        // ---- cross attention ----
        norm_rows<0><<<T_DIM / 4, B, 0, stream>>>(xbuf, hh, nullptr, nullptr, nullptr);
        gemm_nt<64, 2><<<dim3(256), B, 0, stream>>>(hh, 512, cqT + (size_t)l * SQ, 512,
            512, 512, 8, nullptr, nullptr, qb, nullptr, nullptr, 512);
        gemm_nt<64, 6><<<dim3(512), B, 0, stream>>>(enc16, 512, ckvT + (size_t)l * KVZ, 512,
            1024, 512, 16, nullptr, nullptr, nullptr, kb, vT, 4096);
        gemm_nt<128, 0><<<dim3(1024), B, 0, stream>>>(qb, 512, kb, 512,
            4096, 512, 32, nullptr, logits, nullptr, nullptr, nullptr, 0);
        softmax_rows<<<dim3(T_DIM), B, 0, stream>>>(logits, crossb);
        gemm_nt<64, 2><<<dim3(256), B, 0, stream>>>((half_t*)logits, 8192, vT, 4096,
            512, 4096, 8, nullptr, nullptr, ao, nullptr, nullptr, 512);
        gemm_nt<64, 1><<<dim3(256), B, 0, stream>>>(ao, 512, coT + (size_t)l * SQ, 512,
            512, 512, 8, xbuf, xbuf, nullptr, nullptr, nullptr, 0);

        // ---- FFN ----
        norm_rows<0><<<T_DIM / 4, B, 0, stream>>>(xbuf, hh, nullptr, nullptr, nullptr);
        gemm_nt<128, 4><<<dim3(512), B, 0, stream>>>(hh, 512, w1T + (size_t)l * FZ, 512,
            2048, 512, 16, nullptr, nullptr, mid, nullptr, nullptr, 2048);
        gemm_nt<64, 1><<<dim3(256), B, 0, stream>>>(mid, 2048, w2T + (size_t)l * FZ, 2048,
            512, 2048, 8, xbuf, xbuf, nullptr, nullptr, nullptr, 0);
    }

    norm_rows<1><<<T_DIM / 4, B, 0, stream>>>(xbuf, nullptr, outp, alphap, gammap);
}

// Round 4
// 1375.558 us; speedup vs baseline: 2.1419x; 1.0205x over previous
//
#include <hip/hip_runtime.h>
#include <math.h>

typedef _Float16 half_t;
typedef unsigned int u32;
typedef unsigned short u16;
typedef float f32x4 __attribute__((ext_vector_type(4)));
typedef _Float16 f16x8 __attribute__((ext_vector_type(8)));
typedef _Float16 f16x4 __attribute__((ext_vector_type(4)));

#define T_DIM 4096
#define S_DIM 4096
#define D_DIM 512
#define F_DIM 2048
#define NLAYER 4

__device__ __forceinline__ void gload16(const void* g, void* l) {
    __builtin_amdgcn_global_load_lds(
        (const __attribute__((address_space(1))) u32*)g,
        (__attribute__((address_space(3))) u32*)l, 16, 0, 0);
}

// ---------------------------------------------------------------------------
// GEMM: C[M,N] = A[M,K] * B[N,K]^T, fp16 in, fp32 MFMA acc.
// Double-buffered LDS, one barrier per K-step.
// LDS bank-conflict fix (T2, m173 pattern): LDS dest stays linear
// (global_load_lds requirement); the GLOBAL source 16B-slot is pre-swizzled
// per lane (slot ^ ((row>>1)&3)), and fragment reads apply the same XOR
// (kqa = kq ^ ((rr>>1)&3)). Rows 0..7 then hit all 8 bank-groups -> conflict-
// free (2-way over 16 rows = free).
// EPI: 0 f32 store | 1 f32 Cin+acc | 2 fp16 [M,N] | 3 fp16 [N,M] (ldd)
//      4 relu fp16 [M,N] | 5 QKV split (D1=q,D2=k row-major 512; D3=vT ldd)
//      6 KV split (D2=k; D3=vT ldd)
// ---------------------------------------------------------------------------
template<int BN, int EPI>
__global__ __launch_bounds__(256)
void gemm_nt(const half_t* __restrict__ A, int lda,
             const half_t* __restrict__ B, int ldb,
             int N, int K, int gx,
             const float* __restrict__ Cin, float* __restrict__ Cout,
             half_t* __restrict__ D1, half_t* __restrict__ D2,
             half_t* __restrict__ D3, int ldd)
{
    constexpr int BM = 128, BK = 32;
    constexpr int NF = BN / 32;
    __shared__ half_t As[2][BM * BK];
    __shared__ half_t Bs[2][BN * BK];

    const int tid  = threadIdx.x;
    const int wave = tid >> 6;
    const int lane = tid & 63;

    // XCD-aware swizzle (bijective: gridDim.x % 8 == 0 for all launches)
    const int nb  = gridDim.x;
    const int bid = blockIdx.x;
    const int nid = (bid & 7) * (nb >> 3) + (bid >> 3);
    const int bx = nid % gx, by = nid / gx;
    const int bm = by * BM, bn = bx * BN;

    const int wm = (wave >> 1) * 64;
    const int wn = (wave & 1) * (BN / 2);
    const int kq = lane >> 4;
    const int rr = lane & 15;
    const int srow = lane >> 2;
    // pre-swizzled global 16B-slot: slot' = (lane&3) ^ ((srow>>1)&3)
    const int scol = (((lane & 3) ^ ((lane >> 3) & 3)) << 3);
    // fragment-read slot: kqa = kq ^ ((rr>>1)&3) (wm/wn/m*16 are mult of 16)
    const int kqa = kq ^ ((rr >> 1) & 3);

    const half_t* Abase = A + (size_t)(bm + wave * 16 + srow) * lda + scol;
    const half_t* Bbase = B + (size_t)(bn + wave * 16 + srow) * ldb + scol;

    f32x4 acc[4][NF];
#pragma unroll
    for (int m = 0; m < 4; ++m)
#pragma unroll
        for (int n = 0; n < NF; ++n)
            acc[m][n] = f32x4{0.f, 0.f, 0.f, 0.f};

    auto stage = [&](int buf, int k0) {
#pragma unroll
        for (int c = 0; c < 2; ++c)
            gload16(Abase + (size_t)c * 64 * lda + k0,
                    (char*)&As[buf][0] + c * 4096 + wave * 1024 + lane * 16);
#pragma unroll
        for (int c = 0; c < BN / 64; ++c)
            gload16(Bbase + (size_t)c * 64 * ldb + k0,
                    (char*)&Bs[buf][0] + c * 4096 + wave * 1024 + lane * 16);
    };

    const int nt = K / BK;
    stage(0, 0);
    int cur = 0;
    for (int t = 0; t < nt; ++t) {
        __syncthreads();                        // buf[cur] ready (drains vmcnt)
        if (t + 1 < nt) stage(cur ^ 1, (t + 1) * BK);  // prefetch next tile
        f16x8 af[4], bf[NF];
#pragma unroll
        for (int m = 0; m < 4; ++m)
            af[m] = *(const f16x8*)&As[cur][(wm + m * 16 + rr) * BK + kqa * 8];
#pragma unroll
        for (int n = 0; n < NF; ++n)
            bf[n] = *(const f16x8*)&Bs[cur][(wn + n * 16 + rr) * BK + kqa * 8];
#pragma unroll
        for (int m = 0; m < 4; ++m)
#pragma unroll
            for (int n = 0; n < NF; ++n)
                acc[m][n] = __builtin_amdgcn_mfma_f32_16x16x32_f16(af[m], bf[n], acc[m][n], 0, 0, 0);
        cur ^= 1;
    }

    const int r0 = bm + wm + (lane >> 4) * 4;
#pragma unroll
    for (int m = 0; m < 4; ++m)
#pragma unroll
        for (int n = 0; n < NF; ++n) {
            const int c = bn + wn + n * 16 + rr;
            if (EPI == 0 || EPI == 1) {
#pragma unroll
                for (int i = 0; i < 4; ++i) {
                    const int r = r0 + m * 16 + i;
                    const float v = acc[m][n][i];
                    Cout[(size_t)r * N + c] = (EPI == 1) ? (Cin[(size_t)r * N + c] + v) : v;
                }
            } else if (EPI == 2 || EPI == 4) {
#pragma unroll
                for (int i = 0; i < 4; ++i) {
                    float v = acc[m][n][i];
                    if (EPI == 4) v = fmaxf(v, 0.f);
                    D1[(size_t)(r0 + m * 16 + i) * ldd + c] = (half_t)v;
                }
            } else if (EPI == 3) {
                f16x4 hv;
#pragma unroll
                for (int i = 0; i < 4; ++i) hv[i] = (half_t)acc[m][n][i];
                *(f16x4*)&D1[(size_t)c * ldd + r0 + m * 16] = hv;
            } else if (EPI == 5) {
                if (bn < 512) {
#pragma unroll
                    for (int i = 0; i < 4; ++i)
                        D1[(size_t)(r0 + m * 16 + i) * 512 + c] = (half_t)acc[m][n][i];
                } else if (bn < 1024) {
#pragma unroll
                    for (int i = 0; i < 4; ++i)
                        D2[(size_t)(r0 + m * 16 + i) * 512 + (c - 512)] = (half_t)acc[m][n][i];
                } else {
                    f16x4 hv;
#pragma unroll
                    for (int i = 0; i < 4; ++i) hv[i] = (half_t)acc[m][n][i];
                    *(f16x4*)&D3[(size_t)(c - 1024) * ldd + r0 + m * 16] = hv;
                }
            } else { // EPI == 6
                if (bn < 512) {
#pragma unroll
                    for (int i = 0; i < 4; ++i)
                        D2[(size_t)(r0 + m * 16 + i) * 512 + c] = (half_t)acc[m][n][i];
                } else {
                    f16x4 hv;
#pragma unroll
                    for (int i = 0; i < 4; ++i) hv[i] = (half_t)acc[m][n][i];
                    *(f16x4*)&D3[(size_t)(c - 512) * ldd + r0 + m * 16] = hv;
                }
            }
        }
}

// ---------------------------------------------------------------------------
// Row LayerNorm (mean/std ddof=1) over D=512. One wave per row.
// ---------------------------------------------------------------------------
template<int FINAL>
__global__ __launch_bounds__(256)
void norm_rows(const float* __restrict__ x, half_t* __restrict__ hh,
               float* __restrict__ outF, const float* __restrict__ alphaP,
               const float* __restrict__ gammaP)
{
    const int row  = blockIdx.x * 4 + (threadIdx.x >> 6);
    const int lane = threadIdx.x & 63;
    const float* xr = x + (size_t)row * D_DIM + lane * 8;
    float4 a = *(const float4*)xr;
    float4 b = *(const float4*)(xr + 4);
    float v[8] = {a.x, a.y, a.z, a.w, b.x, b.y, b.z, b.w};
    float s = 0.f;
#pragma unroll
    for (int j = 0; j < 8; ++j) s += v[j];
#pragma unroll
    for (int off = 32; off; off >>= 1) s += __shfl_xor(s, off);
    const float mean = s * (1.f / 512.f);
    float ss = 0.f;
#pragma unroll
    for (int j = 0; j < 8; ++j) { float d = v[j] - mean; ss += d * d; }
#pragma unroll
    for (int off = 32; off; off >>= 1) ss += __shfl_xor(ss, off);
    const float inv = 1.f / (sqrtf(ss * (1.f / 511.f)) + 1e-6f);
    if (FINAL) {
        const float alp = alphaP[0], gam = gammaP[0];
        float o[8];
#pragma unroll
        for (int j = 0; j < 8; ++j) o[j] = alp * ((v[j] - mean) * inv) + gam;
        float4 o0 = {o[0], o[1], o[2], o[3]};
        float4 o1 = {o[4], o[5], o[6], o[7]};
        float* op = outF + (size_t)row * D_DIM + lane * 8;
        *(float4*)op = o0;
        *(float4*)(op + 4) = o1;
    } else {
        f16x8 hv;
#pragma unroll
        for (int j = 0; j < 8; ++j) hv[j] = (half_t)((v[j] - mean) * inv);
        *(f16x8*)&hh[(size_t)row * D_DIM + lane * 8] = hv;
    }
}

__global__ __launch_bounds__(256)
void cast_f16(const float* __restrict__ in, half_t* __restrict__ out)
{
    size_t i = ((size_t)blockIdx.x * 256 + threadIdx.x) * 8;
    float4 a = *(const float4*)&in[i];
    float4 b = *(const float4*)&in[i + 4];
    float v[8] = {a.x, a.y, a.z, a.w, b.x, b.y, b.z, b.w};
    f16x8 o;
#pragma unroll
    for (int j = 0; j < 8; ++j) o[j] = (half_t)v[j];
    *(f16x8*)&out[i] = o;
}

// transpose [R,C] fp32 -> [C,R] fp16 (with scale); per-layer strides inZ/outZ
__global__ __launch_bounds__(256)
void transpose_cast(const float* __restrict__ in, half_t* __restrict__ out,
                    int R, int C, float scale, int inZ, int outZ)
{
    in  += (size_t)blockIdx.z * inZ;
    out += (size_t)blockIdx.z * outZ;
    __shared__ float tile[32][33];
    const int tx = threadIdx.x & 31, ty = threadIdx.x >> 5;
    const int r0 = blockIdx.y * 32, c0 = blockIdx.x * 32;
#pragma unroll
    for (int i = 0; i < 4; ++i)
        tile[ty + i * 8][tx] = in[(size_t)(r0 + ty + i * 8) * C + c0 + tx];
    __syncthreads();
#pragma unroll
    for (int i = 0; i < 4; ++i)
        out[(size_t)(c0 + ty + i * 8) * R + r0 + tx] = (half_t)(tile[tx][ty + i * 8] * scale);
}

// ---------------------------------------------------------------------------
// Mask packing: one block per row t. Cross bits from one coalesced pass over
// cm row (built in LDS), self bits gathered from the 512B LDS word array.
// ---------------------------------------------------------------------------
__global__ __launch_bounds__(256)
void pack_masks(const float* __restrict__ cm, const int* __restrict__ ids,
                u32* __restrict__ crossb, u32* __restrict__ selfb)
{
    const int t = blockIdx.x;
    const float* row = cm + (size_t)t * S_DIM;
    __shared__ u32 cb[S_DIM / 32];   // 128 words
    __shared__ u16 sh16[256];
    const int tid = threadIdx.x;
    u32 bits = 0;
#pragma unroll
    for (int q = 0; q < 4; ++q) {
        float4 v = *(const float4*)&row[tid * 16 + q * 4];
        bits |= (v.x > 0.5f ? 1u : 0u) << (q * 4 + 0);
        bits |= (v.y > 0.5f ? 1u : 0u) << (q * 4 + 1);
        bits |= (v.z > 0.5f ? 1u : 0u) << (q * 4 + 2);
        bits |= (v.w > 0.5f ? 1u : 0u) << (q * 4 + 3);
    }
    ((u16*)cb)[tid] = (u16)bits;
    __syncthreads();
    u32 sb = 0;
#pragma unroll
    for (int q = 0; q < 4; ++q) {
        int4 id4 = *(const int4*)&ids[tid * 16 + q * 4];
        sb |= ((cb[id4.x >> 5] >> (id4.x & 31)) & 1u) << (q * 4 + 0);
        sb |= ((cb[id4.y >> 5] >> (id4.y & 31)) & 1u) << (q * 4 + 1);
        sb |= ((cb[id4.z >> 5] >> (id4.z & 31)) & 1u) << (q * 4 + 2);
        sb |= ((cb[id4.w >> 5] >> (id4.w & 31)) & 1u) << (q * 4 + 3);
    }
    sh16[tid] = (u16)sb;
    __syncthreads();
    if (tid < 128) {
        crossb[(size_t)t * 128 + tid] = cb[tid];
        selfb[(size_t)t * 128 + tid]  = (u32)sh16[2 * tid] | ((u32)sh16[2 * tid + 1] << 16);
    }
}

// ---------------------------------------------------------------------------
// Row softmax over S=4096 (logits pre-scaled; mask from packed bits),
// in-place: reads f32 logits row, writes P fp16 at row start.
// ---------------------------------------------------------------------------
__global__ __launch_bounds__(256)
void softmax_rows(float* __restrict__ logits, const u32* __restrict__ bits)
{
    const int t = blockIdx.x;
    float* row = logits + (size_t)t * S_DIM;
    const u32* bw = bits + (size_t)t * (S_DIM / 32);
    __shared__ float red[8];
    const int tid = threadIdx.x, wave = tid >> 6, lane = tid & 63;
    float z[16];
    float lmax = -3.0e38f;
#pragma unroll
    for (int j = 0; j < 4; ++j) {
        const int s = j * 1024 + tid * 4;
        float4 v = *(const float4*)&row[s];
        const u32 w = bw[s >> 5];
        const int sh = s & 31;
        z[j * 4 + 0] = v.x + (((w >> (sh + 0)) & 1u) ? 0.f : -1e9f);
        z[j * 4 + 1] = v.y + (((w >> (sh + 1)) & 1u) ? 0.f : -1e9f);
        z[j * 4 + 2] = v.z + (((w >> (sh + 2)) & 1u) ? 0.f : -1e9f);
        z[j * 4 + 3] = v.w + (((w >> (sh + 3)) & 1u) ? 0.f : -1e9f);
        lmax = fmaxf(lmax, fmaxf(fmaxf(z[j*4], z[j*4+1]), fmaxf(z[j*4+2], z[j*4+3])));
    }
#pragma unroll
    for (int off = 32; off; off >>= 1) lmax = fmaxf(lmax, __shfl_xor(lmax, off));
    if (lane == 0) red[wave] = lmax;
    __syncthreads();
    const float mx = fmaxf(fmaxf(red[0], red[1]), fmaxf(red[2], red[3]));
    float lsum = 0.f;
#pragma unroll
    for (int q = 0; q < 16; ++q) { z[q] = __expf(z[q] - mx); lsum += z[q]; }
#pragma unroll
    for (int off = 32; off; off >>= 1) lsum += __shfl_xor(lsum, off);
    if (lane == 0) red[4 + wave] = lsum;
    __syncthreads();
    const float inv = 1.f / (red[4] + red[5] + red[6] + red[7]);
    half_t* ph = (half_t*)row;
#pragma unroll
    for (int j = 0; j < 4; ++j) {
        const int s = j * 1024 + tid * 4;
        f16x4 hv;
#pragma unroll
        for (int q = 0; q < 4; ++q) hv[q] = (half_t)(z[j * 4 + q] * inv);
        *(f16x4*)&ph[s] = hv;
    }
}

// ---------------------------------------------------------------------------
extern "C" void kernel_launch(void* const* d_in, const int* in_sizes, int n_in,
                              void* d_out, int out_size, void* d_ws, size_t ws_size,
                              hipStream_t stream)
{
    (void)in_sizes; (void)n_in; (void)out_size; (void)ws_size;

    const float* x0p  = (const float*)d_in[0];
    const float* encp = (const float*)d_in[1];
    const float* cmp  = (const float*)d_in[2];
    const float* Wq = (const float*)d_in[3], *Wk = (const float*)d_in[4];
    const float* Wv = (const float*)d_in[5], *Wo = (const float*)d_in[6];
    const float* Cq = (const float*)d_in[7], *Ck = (const float*)d_in[8];
    const float* Cv = (const float*)d_in[9], *Co = (const float*)d_in[10];
    const float* W1p = (const float*)d_in[11];
    const float* W2p = (const float*)d_in[12];
    const float* alphap = (const float*)d_in[13];
    const float* gammap = (const float*)d_in[14];
    const int*   idsp   = (const int*)d_in[15];
    float* outp = (float*)d_out;

    char* wp = (char*)d_ws;
    auto take = [&](size_t nelem, int esz) -> void* {
        void* p = (void*)wp;
        wp += (nelem * (size_t)esz + 255) & ~(size_t)255;
        return p;
    };
    half_t* wqkvT = (half_t*)take((size_t)NLAYER * 1536 * 512, 2);
    half_t* ckvT  = (half_t*)take((size_t)NLAYER * 1024 * 512, 2);
    half_t* cqT   = (half_t*)take((size_t)NLAYER * 512 * 512, 2);
    half_t* woT   = (half_t*)take((size_t)NLAYER * 512 * 512, 2);
    half_t* coT   = (half_t*)take((size_t)NLAYER * 512 * 512, 2);
    half_t* w1T   = (half_t*)take((size_t)NLAYER * D_DIM * F_DIM, 2);
    half_t* w2T   = (half_t*)take((size_t)NLAYER * D_DIM * F_DIM, 2);
    half_t* hh    = (half_t*)take((size_t)T_DIM * D_DIM, 2);
    half_t* qb    = (half_t*)take((size_t)T_DIM * D_DIM, 2);
    half_t* kb    = (half_t*)take((size_t)S_DIM * D_DIM, 2);
    half_t* vT    = (half_t*)take((size_t)S_DIM * D_DIM, 2);
    half_t* ao    = (half_t*)take((size_t)T_DIM * D_DIM, 2);
    half_t* mid   = (half_t*)take((size_t)T_DIM * F_DIM, 2);
    half_t* enc16 = (half_t*)take((size_t)S_DIM * D_DIM, 2);
    float* xbuf   = (float*)take((size_t)T_DIM * D_DIM, 4);
    float* logits = (float*)take((size_t)T_DIM * S_DIM, 4);
    u32* crossb = (u32*)take((size_t)T_DIM * (S_DIM / 32), 4);
    u32* selfb  = (u32*)take((size_t)T_DIM * (S_DIM / 32), 4);

    const dim3 B(256);
    const float qscale = 0.04419417382415922f; // 1/sqrt(512), folded into Wq/Cq

    // ---- one-time prep ----
    const int SQ = 512 * 512, QKVZ = 1536 * 512, KVZ = 1024 * 512, FZ = 512 * 2048;
    transpose_cast<<<dim3(16,16,4), B, 0, stream>>>(Wq, wqkvT,            512, 512, qscale, SQ, QKVZ);
    transpose_cast<<<dim3(16,16,4), B, 0, stream>>>(Wk, wqkvT + SQ,       512, 512, 1.f,    SQ, QKVZ);
    transpose_cast<<<dim3(16,16,4), B, 0, stream>>>(Wv, wqkvT + 2 * SQ,   512, 512, 1.f,    SQ, QKVZ);
    transpose_cast<<<dim3(16,16,4), B, 0, stream>>>(Wo, woT,              512, 512, 1.f,    SQ, SQ);
    transpose_cast<<<dim3(16,16,4), B, 0, stream>>>(Cq, cqT,              512, 512, qscale, SQ, SQ);
    transpose_cast<<<dim3(16,16,4), B, 0, stream>>>(Ck, ckvT,             512, 512, 1.f,    SQ, KVZ);
    transpose_cast<<<dim3(16,16,4), B, 0, stream>>>(Cv, ckvT + SQ,        512, 512, 1.f,    SQ, KVZ);
    transpose_cast<<<dim3(16,16,4), B, 0, stream>>>(Co, coT,              512, 512, 1.f,    SQ, SQ);
    transpose_cast<<<dim3(64,16,4), B, 0, stream>>>(W1p, w1T, 512, 2048, 1.f, FZ, FZ);
    transpose_cast<<<dim3(16,64,4), B, 0, stream>>>(W2p, w2T, 2048, 512, 1.f, FZ, FZ);
    cast_f16<<<dim3((S_DIM * D_DIM / 8) / 256), B, 0, stream>>>(encp, enc16);
    pack_masks<<<dim3(T_DIM), B, 0, stream>>>(cmp, idsp, crossb, selfb);

    for (int l = 0; l < NLAYER; ++l) {
        const float* xin = (l == 0) ? x0p : xbuf;

        // ---- self attention ----
        norm_rows<0><<<T_DIM / 4, B, 0, stream>>>(xin, hh, nullptr, nullptr, nullptr);
        gemm_nt<64, 5><<<dim3(768), B, 0, stream>>>(hh, 512, wqkvT + (size_t)l * QKVZ, 512,
            1536, 512, 24, nullptr, nullptr, qb, kb, vT, 4096);
        gemm_nt<128, 0><<<dim3(1024), B, 0, stream>>>(qb, 512, kb, 512,
            4096, 512, 32, nullptr, logits, nullptr, nullptr, nullptr, 0);
        softmax_rows<<<dim3(T_DIM), B, 0, stream>>>(logits, selfb);
        gemm_nt<64, 2><<<dim3(256), B, 0, stream>>>((half_t*)logits, 8192, vT, 4096,
            512, 4096, 8, nullptr, nullptr, ao, nullptr, nullptr, 512);
        gemm_nt<64, 1><<<dim3(256), B, 0, stream>>>(ao, 512, woT + (size_t)l * SQ, 512,
            512, 512, 8, xin, xbuf, nullptr, nullptr, nullptr, 0);

        // ---- cross attention ----
        norm_rows<0><<<T_DIM / 4, B, 0, stream>>>(xbuf, hh, nullptr, nullptr, nullptr);
        gemm_nt<64, 2><<<dim3(256), B, 0, stream>>>(hh, 512, cqT + (size_t)l * SQ, 512,
            512, 512, 8, nullptr, nullptr, qb, nullptr, nullptr, 512);
        gemm_nt<64, 6><<<dim3(512), B, 0, stream>>>(enc16, 512, ckvT + (size_t)l * KVZ, 512,
            1024, 512, 16, nullptr, nullptr, nullptr, kb, vT, 4096);
        gemm_nt<128, 0><<<dim3(1024), B, 0, stream>>>(qb, 512, kb, 512,
            4096, 512, 32, nullptr, logits, nullptr, nullptr, nullptr, 0);
        softmax_rows<<<dim3(T_DIM), B, 0, stream>>>(logits, crossb);
        gemm_nt<64, 2><<<dim3(256), B, 0, stream>>>((half_t*)logits, 8192, vT, 4096,
            512, 4096, 8, nullptr, nullptr, ao, nullptr, nullptr, 512);
        gemm_nt<64, 1><<<dim3(256), B, 0, stream>>>(ao, 512, coT + (size_t)l * SQ, 512,
            512, 512, 8, xbuf, xbuf, nullptr, nullptr, nullptr, 0);

        // ---- FFN ----
        norm_rows<0><<<T_DIM / 4, B, 0, stream>>>(xbuf, hh, nullptr, nullptr, nullptr);
        gemm_nt<128, 4><<<dim3(512), B, 0, stream>>>(hh, 512, w1T + (size_t)l * FZ, 512,
            2048, 512, 16, nullptr, nullptr, mid, nullptr, nullptr, 2048);
        gemm_nt<64, 1><<<dim3(256), B, 0, stream>>>(mid, 2048, w2T + (size_t)l * FZ, 2048,
            512, 2048, 8, xbuf, xbuf, nullptr, nullptr, nullptr, 0);
    }

    norm_rows<1><<<T_DIM / 4, B, 0, stream>>>(xbuf, nullptr, outp, alphap, gammap);
}